// Round 1
// baseline (379.586 us; speedup 1.0000x reference)
//
#include <hip/hip_runtime.h>
#include <hip/hip_bf16.h>
#include <cstdint>

// MHD PINN loss, fully fused. N=131072 pts, H=256.
// Streams: s=0 -> h (forward), s=1..3 -> tangents d/dx,d/dy,d/dt.
// Per block: 16 points -> M = 4*16 = 64 GEMM rows. 4 waves, each owns 64 out cols.

#define LDW 264   // X tile row stride in ushorts (256 + 8 pad -> 2-way-max bank aliasing)
#define TPTS 16   // points per block

typedef __attribute__((ext_vector_type(8))) short v8h;   // 8 x bf16
typedef __attribute__((ext_vector_type(4))) float v4f;

__device__ __forceinline__ ushort f2b(float f) {           // fp32 -> bf16 RNE
    uint32_t u = __float_as_uint(f);
    u = (u + 0x7fffu + ((u >> 16) & 1u)) >> 16;
    return (ushort)u;
}

__device__ __forceinline__ float fast_tanh(float x) {
    // tanh(x) = 1 - 2/(exp(2x)+1); v_exp_f32 + v_rcp_f32, ~1e-6 abs err (<< bf16 noise)
    float e = __expf(2.0f * x);
    return 1.0f - 2.0f * __builtin_amdgcn_rcpf(e + 1.0f);
}

// ---- prep: W2,W3 (256x256 row-major [k][n]) -> bf16 transposed Wt[n][k]; W4 (256x6) -> Wt4[16][256] padded
__global__ void prep_weights(const float* __restrict__ W2, const float* __restrict__ W3,
                             const float* __restrict__ W4,
                             ushort* __restrict__ Wt2, ushort* __restrict__ Wt3,
                             ushort* __restrict__ Wt4) {
    int idx = blockIdx.x * 256 + threadIdx.x;
    if (idx < 65536) {
        int k = idx >> 8, n = idx & 255;
        Wt2[n * 256 + k] = f2b(W2[k * 256 + n]);
        Wt3[n * 256 + k] = f2b(W3[k * 256 + n]);
    }
    if (idx < 4096) {
        int n = idx >> 8, k = idx & 255;   // n in [0,16), k in [0,256)
        Wt4[n * 256 + k] = (n < 6) ? f2b(W4[k * 6 + n]) : (ushort)0;
    }
}

// ---- one hidden dense layer (256->256) on the 64-row stacked tile, in-place in LDS
__device__ __forceinline__ void dense_layer(ushort* Xs, const ushort* __restrict__ Wt,
                                            const float* __restrict__ bias,
                                            int lane, int wv) {
    const int q = lane >> 4, l15 = lane & 15;
    v4f acc[4][4];
    #pragma unroll
    for (int a = 0; a < 4; a++)
        #pragma unroll
        for (int b = 0; b < 4; b++) {
            v4f z = {0.0f, 0.0f, 0.0f, 0.0f};
            acc[a][b] = z;
        }
    const int kq = q * 8;
    #pragma unroll
    for (int kk = 0; kk < 8; kk++) {
        const int ko = kk * 32 + kq;
        v8h A[4], B[4];
        #pragma unroll
        for (int mt = 0; mt < 4; mt++)
            A[mt] = *(const v8h*)(&Xs[(mt * 16 + l15) * LDW + ko]);
        #pragma unroll
        for (int nt = 0; nt < 4; nt++)
            B[nt] = *(const v8h*)(&Wt[(wv * 64 + nt * 16 + l15) * 256 + ko]);
        #pragma unroll
        for (int mt = 0; mt < 4; mt++)
            #pragma unroll
            for (int nt = 0; nt < 4; nt++)
                acc[mt][nt] = __builtin_amdgcn_mfma_f32_16x16x32_bf16(A[mt], B[nt], acc[mt][nt], 0, 0, 0);
    }
    __syncthreads();   // all reads of Xs done before in-place overwrite
    // epilogue: h = tanh(y0 + b); tangents scaled by (1-h^2). Same lane holds matching (p,col)
    // across all 4 streams (stream == m-tile, C/D row = q*4+reg).
    #pragma unroll
    for (int nt = 0; nt < 4; nt++) {
        const int col = wv * 64 + nt * 16 + l15;
        const float bb = bias[col];
        #pragma unroll
        for (int r = 0; r < 4; r++) {
            const int p = q * 4 + r;
            float h = fast_tanh(acc[0][nt][r] + bb);
            float d = 1.0f - h * h;
            Xs[p * LDW + col]        = f2b(h);
            Xs[(16 + p) * LDW + col] = f2b(d * acc[1][nt][r]);
            Xs[(32 + p) * LDW + col] = f2b(d * acc[2][nt][r]);
            Xs[(48 + p) * LDW + col] = f2b(d * acc[3][nt][r]);
        }
    }
    __syncthreads();
}

__global__ __launch_bounds__(256, 2)
void mhd_fused(const float* __restrict__ coords,
               const float* __restrict__ W1, const float* __restrict__ b1,
               const float* __restrict__ b2, const float* __restrict__ b3,
               const float* __restrict__ b4,
               const float* __restrict__ wts,
               const ushort* __restrict__ Wt2, const ushort* __restrict__ Wt3,
               const ushort* __restrict__ Wt4,
               float* __restrict__ out, int npts, float inv_n) {
    __shared__ ushort Xs[64 * LDW];
    __shared__ float  cs[TPTS * 3];
    __shared__ float  Y4[4 * TPTS * 6];

    const int tid  = threadIdx.x;
    const int lane = tid & 63;
    const int wv   = tid >> 6;
    const int q    = lane >> 4;
    const int l15  = lane & 15;
    const int base = blockIdx.x * TPTS;

    if (tid < TPTS * 3) {
        int p = tid / 3, c = tid % 3;
        int gp = base + p; if (gp >= npts) gp = npts - 1;
        cs[tid] = coords[gp * 3 + c];
    }
    __syncthreads();

    // ---- layer 1 (3->256) + tangent seeds th1_k = (1-h^2) * W1[k,:]
    {
        const int j = tid;  // 256 threads == 256 cols
        float w0 = W1[j], w1 = W1[256 + j], w2 = W1[512 + j], bb = b1[j];
        #pragma unroll
        for (int p = 0; p < TPTS; p++) {
            float x = cs[p * 3], y = cs[p * 3 + 1], t = cs[p * 3 + 2];
            float pre = fmaf(x, w0, fmaf(y, w1, fmaf(t, w2, bb)));
            float h = fast_tanh(pre);
            float d = 1.0f - h * h;
            Xs[p * LDW + j]        = f2b(h);
            Xs[(16 + p) * LDW + j] = f2b(d * w0);
            Xs[(32 + p) * LDW + j] = f2b(d * w1);
            Xs[(48 + p) * LDW + j] = f2b(d * w2);
        }
    }
    __syncthreads();

    // ---- layers 2 and 3 (256->256, fused tangent propagation)
    dense_layer(Xs, Wt2, b2, lane, wv);
    dense_layer(Xs, Wt3, b3, lane, wv);

    // ---- layer 4 (256->6, padded to 16 cols): wave wv computes stream wv
    {
        v4f acc = {0.0f, 0.0f, 0.0f, 0.0f};
        #pragma unroll
        for (int kk = 0; kk < 8; kk++) {
            const int ko = kk * 32 + q * 8;
            v8h A = *(const v8h*)(&Xs[(wv * 16 + l15) * LDW + ko]);
            v8h B = *(const v8h*)(&Wt4[l15 * 256 + ko]);
            acc = __builtin_amdgcn_mfma_f32_16x16x32_bf16(A, B, acc, 0, 0, 0);
        }
        if (l15 < 6) {
            #pragma unroll
            for (int r = 0; r < 4; r++) {
                const int p = q * 4 + r;
                Y4[(wv * 16 + p) * 6 + l15] = acc[r];
            }
        }
    }
    __syncthreads();

    // ---- residuals (threads 0..15, one point each) + reduce + atomic
    float v = 0.0f;
    if (tid < 16 && (base + tid) < npts) {
        const float* Yh = &Y4[(0 * 16 + tid) * 6];
        const float* JX = &Y4[(1 * 16 + tid) * 6];
        const float* JY = &Y4[(2 * 16 + tid) * 6];
        const float* JT = &Y4[(3 * 16 + tid) * 6];
        const float g1 = 1.5f; // 1/(gamma-1), gamma = 5/3
        float rho = Yh[0] + b4[0], vx = Yh[1] + b4[1], vy = Yh[2] + b4[2];
        float Bx  = Yh[3] + b4[3], By = Yh[4] + b4[4], P  = Yh[5] + b4[5];
        float v2 = vx * vx + vy * vy;
        float dt_rho = JT[0];
        float dt_rhovx = dt_rho * vx + rho * JT[1];
        float dt_rhovy = dt_rho * vy + rho * JT[2];
        auto dE = [&](const float* J) {
            return J[5] * g1 + 0.5f * J[0] * v2 + rho * (vx * J[1] + vy * J[2]) + Bx * J[3] + By * J[4];
        };
        float dE_dx = dE(JX), dE_dy = dE(JY), dE_dt = dE(JT);
        float div_v = JX[1] + JY[2];
        float div_B = JX[3] + JY[4];
        float continuity = dt_rho + rho * div_v;
        float dPm_dx = JX[5] + Bx * JX[3] + By * JX[4];
        float dPm_dy = JY[5] + Bx * JY[3] + By * JY[4];
        float momentum_x = dt_rhovx + dPm_dx - (Bx * JX[3] + By * JY[3]);
        float momentum_y = dt_rhovy + dPm_dy - (Bx * JX[4] + By * JY[4]);
        auto dG = [&](const float* J) {
            return J[1] * By + vx * J[4] - J[2] * Bx - vy * J[3];
        };
        float induction_x = JT[3] + dG(JY);
        float induction_y = JT[4] - dG(JX);
        float E = P * g1 + 0.5f * rho * v2 + 0.5f * (Bx * Bx + By * By);
        float S = E + P + 0.5f * (Bx * Bx + By * By);
        float dS_dx = dE_dx + JX[5] + Bx * JX[3] + By * JX[4];
        float dS_dy = dE_dy + JY[5] + Bx * JY[3] + By * JY[4];
        float D = Bx * vx + By * vy;
        auto dD = [&](const float* J) {
            return J[3] * vx + Bx * J[1] + J[4] * vy + By * J[2];
        };
        float dFx_dx = dS_dx * vx + S * JX[1] - dD(JX) * Bx - D * JX[3];
        float dFy_dy = dS_dy * vy + S * JY[2] - dD(JY) * By - D * JY[4];
        float energy = dE_dt + dFx_dx + dFy_dy;
        v = wts[0] * continuity * continuity
          + wts[1] * momentum_x * momentum_x
          + wts[2] * momentum_y * momentum_y
          + wts[3] * induction_x * induction_x
          + wts[4] * induction_y * induction_y
          + wts[5] * energy * energy
          + wts[6] * div_B * div_B;
    }
    if (tid < 64) {
        #pragma unroll
        for (int off = 8; off >= 1; off >>= 1)
            v += __shfl_down(v, off, 64);
        if (tid == 0) atomicAdd(out, v * inv_n);
    }
}

extern "C" void kernel_launch(void* const* d_in, const int* in_sizes, int n_in,
                              void* d_out, int out_size, void* d_ws, size_t ws_size,
                              hipStream_t stream) {
    const float* coords = (const float*)d_in[0];
    const float* W1 = (const float*)d_in[1];
    const float* b1 = (const float*)d_in[2];
    const float* W2 = (const float*)d_in[3];
    const float* b2 = (const float*)d_in[4];
    const float* W3 = (const float*)d_in[5];
    const float* b3 = (const float*)d_in[6];
    const float* W4 = (const float*)d_in[7];
    const float* b4 = (const float*)d_in[8];
    const float* wts = (const float*)d_in[9];
    const int npts = in_sizes[0] / 3;

    ushort* Wt2 = (ushort*)d_ws;
    ushort* Wt3 = Wt2 + 65536;
    ushort* Wt4 = Wt3 + 65536;

    hipMemsetAsync(d_out, 0, sizeof(float), stream);
    prep_weights<<<256, 256, 0, stream>>>(W2, W3, W4, Wt2, Wt3, Wt4);
    const int nb = (npts + TPTS - 1) / TPTS;
    mhd_fused<<<nb, 256, 0, stream>>>(coords, W1, b1, b2, b3, b4, wts,
                                      Wt2, Wt3, Wt4, (float*)d_out, npts, 1.0f / npts);
}

// Round 2
// 296.836 us; speedup vs baseline: 1.2788x; 1.2788x over previous
//
#include <hip/hip_runtime.h>
#include <hip/hip_bf16.h>
#include <cstdint>

// MHD PINN loss, fully fused + persistent. N=131072 pts, H=256.
// Swapped-operand formulation: D = W * X^T (m = out-neuron, n = 16pts x 4 streams).
// Each wave owns 64 output neurons; W2/W3/W4 fragments live in REGISTERS for the
// whole kernel (persistent grid = 256 blocks, 1 block/CU, 1 wave/SIMD).
// Streams: s=0 -> h (forward), s=1..3 -> tangents d/dx,d/dy,d/dt; X row = s*16+p.

#define LDW 264   // X tile row stride in ushorts (256 + 8 pad)
#define TPTS 16   // points per tile
#define GRIDB 256

typedef __attribute__((ext_vector_type(8))) short v8h;   // 8 x bf16 (one MFMA operand)
typedef __attribute__((ext_vector_type(4))) float v4f;

__device__ __forceinline__ ushort f2b(float f) {           // fp32 -> bf16 RNE
    uint32_t u = __float_as_uint(f);
    u = (u + 0x7fffu + ((u >> 16) & 1u)) >> 16;
    return (ushort)u;
}
__device__ __forceinline__ uint32_t pk2(float a, float b) {
    return (uint32_t)f2b(a) | ((uint32_t)f2b(b) << 16);
}

__device__ __forceinline__ float fast_tanh(float x) {
    float e = __expf(2.0f * x);
    return 1.0f - 2.0f * __builtin_amdgcn_rcpf(e + 1.0f);
}

// prep: W2,W3 (256x256 row-major [k][n]) -> bf16 transposed Wt[n][k]; W4 (256x6) -> Wt4[16][256]
__global__ void prep_weights(const float* __restrict__ W2, const float* __restrict__ W3,
                             const float* __restrict__ W4,
                             ushort* __restrict__ Wt2, ushort* __restrict__ Wt3,
                             ushort* __restrict__ Wt4) {
    int idx = blockIdx.x * 256 + threadIdx.x;
    if (idx < 65536) {
        int k = idx >> 8, n = idx & 255;
        Wt2[n * 256 + k] = f2b(W2[k * 256 + n]);
        Wt3[n * 256 + k] = f2b(W3[k * 256 + n]);
    }
    if (idx < 4096) {
        int n = idx >> 8, k = idx & 255;
        Wt4[n * 256 + k] = (n < 6) ? f2b(W4[k * 6 + n]) : (ushort)0;
    }
}

__global__ __launch_bounds__(256, 1)
void mhd_fused(const float* __restrict__ coords,
               const float* __restrict__ W1, const float* __restrict__ b1,
               const float* __restrict__ b2, const float* __restrict__ b3,
               const float* __restrict__ b4,
               const float* __restrict__ wts,
               const ushort* __restrict__ Wt2, const ushort* __restrict__ Wt3,
               const ushort* __restrict__ Wt4,
               float* __restrict__ out, int npts, float inv_n) {
    __shared__ ushort Xs[64 * LDW];
    __shared__ float  cs[TPTS * 3];
    __shared__ float  Y4[4][TPTS][8];

    const int tid  = threadIdx.x;
    const int lane = tid & 63;
    const int wv   = tid >> 6;
    const int q    = lane >> 4;
    const int l15  = lane & 15;

    // ---- one-time: weight fragments -> registers ------------------------------
    v8h w2f[4][8], w3f[4][8], w4f[8];
    v4f bs2[4], bs3[4];
    #pragma unroll
    for (int mt = 0; mt < 4; mt++) {
        const int nrow = (wv * 64 + mt * 16 + l15) * 256 + q * 8;
        #pragma unroll
        for (int kk = 0; kk < 8; kk++) {
            w2f[mt][kk] = *(const v8h*)(&Wt2[nrow + kk * 32]);
            w3f[mt][kk] = *(const v8h*)(&Wt3[nrow + kk * 32]);
        }
        bs2[mt] = *(const v4f*)(&b2[wv * 64 + mt * 16 + q * 4]);
        bs3[mt] = *(const v4f*)(&b3[wv * 64 + mt * 16 + q * 4]);
    }
    #pragma unroll
    for (int kk = 0; kk < 8; kk++)
        w4f[kk] = *(const v8h*)(&Wt4[l15 * 256 + kk * 32 + q * 8]);

    const float l1w0 = W1[tid], l1w1 = W1[256 + tid], l1w2 = W1[512 + tid], l1b = b1[tid];
    const float b40 = b4[0], b41 = b4[1], b42 = b4[2], b43 = b4[3], b44 = b4[4], b45 = b4[5];
    const float wt0 = wts[0], wt1 = wts[1], wt2_ = wts[2], wt3_ = wts[3],
                wt4_ = wts[4], wt5 = wts[5], wt6 = wts[6];

    const int ntiles = (npts + TPTS - 1) / TPTS;
    float vsum = 0.0f;

    for (int tile = blockIdx.x; tile < ntiles; tile += gridDim.x) {
        const int base = tile * TPTS;

        if (tid < TPTS * 3) {
            int p = tid / 3, c = tid % 3;
            int gp = base + p; if (gp >= npts) gp = npts - 1;
            cs[tid] = coords[gp * 3 + c];
        }
        __syncthreads();

        // ---- layer 1 (3->256): thread = neuron col j = tid --------------------
        #pragma unroll
        for (int p = 0; p < TPTS; p++) {
            float x = cs[p * 3], y = cs[p * 3 + 1], t = cs[p * 3 + 2];
            float pre = fmaf(x, l1w0, fmaf(y, l1w1, fmaf(t, l1w2, l1b)));
            float h = fast_tanh(pre);
            float d = 1.0f - h * h;
            Xs[p * LDW + tid]        = f2b(h);
            Xs[(16 + p) * LDW + tid] = f2b(d * l1w0);
            Xs[(32 + p) * LDW + tid] = f2b(d * l1w1);
            Xs[(48 + p) * LDW + tid] = f2b(d * l1w2);
        }
        __syncthreads();

        // ---- hidden layers 2,3: D = W(64x256 slice) * X^T(256x64), in-place ----
        #pragma unroll
        for (int L = 0; L < 2; L++) {
            v4f acc[4][4];
            #pragma unroll
            for (int a = 0; a < 4; a++)
                #pragma unroll
                for (int b = 0; b < 4; b++) {
                    v4f z = {0.0f, 0.0f, 0.0f, 0.0f};
                    acc[a][b] = z;
                }
            #pragma unroll
            for (int kk = 0; kk < 8; kk++) {
                v8h B[4];
                #pragma unroll
                for (int nt = 0; nt < 4; nt++)
                    B[nt] = *(const v8h*)(&Xs[(nt * 16 + l15) * LDW + kk * 32 + q * 8]);
                #pragma unroll
                for (int mt = 0; mt < 4; mt++) {
                    v8h A = (L == 0) ? w2f[mt][kk] : w3f[mt][kk];
                    #pragma unroll
                    for (int nt = 0; nt < 4; nt++)
                        acc[mt][nt] = __builtin_amdgcn_mfma_f32_16x16x32_bf16(A, B[nt], acc[mt][nt], 0, 0, 0);
                }
            }
            __syncthreads();   // all B-frag reads done before in-place overwrite
            // epilogue: C/D map (swapped): D row (=neuron) = mt*16+q*4+r, D col (=X row) = nt*16+l15
            // => stream s == nt, point p == l15; 4 consecutive neurons per reg-quad -> b64 writes
            #pragma unroll
            for (int mt = 0; mt < 4; mt++) {
                const int colb = wv * 64 + mt * 16 + q * 4;
                v4f bb = (L == 0) ? bs2[mt] : bs3[mt];
                float h0 = fast_tanh(acc[mt][0][0] + bb[0]);
                float h1 = fast_tanh(acc[mt][0][1] + bb[1]);
                float h2 = fast_tanh(acc[mt][0][2] + bb[2]);
                float h3 = fast_tanh(acc[mt][0][3] + bb[3]);
                float d0 = 1.0f - h0 * h0, d1 = 1.0f - h1 * h1;
                float d2 = 1.0f - h2 * h2, d3 = 1.0f - h3 * h3;
                uint2 w;
                w.x = pk2(h0, h1); w.y = pk2(h2, h3);
                *(uint2*)(&Xs[l15 * LDW + colb]) = w;
                #pragma unroll
                for (int s = 1; s < 4; s++) {
                    w.x = pk2(d0 * acc[mt][s][0], d1 * acc[mt][s][1]);
                    w.y = pk2(d2 * acc[mt][s][2], d3 * acc[mt][s][3]);
                    *(uint2*)(&Xs[(s * 16 + l15) * LDW + colb]) = w;
                }
            }
            __syncthreads();
        }

        // ---- layer 4 (16x256 padded W4t) * X^T, wave wv handles stream wv ------
        {
            v4f a4 = {0.0f, 0.0f, 0.0f, 0.0f};
            #pragma unroll
            for (int kk = 0; kk < 8; kk++) {
                v8h B = *(const v8h*)(&Xs[(wv * 16 + l15) * LDW + kk * 32 + q * 8]);
                a4 = __builtin_amdgcn_mfma_f32_16x16x32_bf16(w4f[kk], B, a4, 0, 0, 0);
            }
            // D row = output idx q*4+r, D col = point l15 (within stream wv)
            if (q < 2) {
                #pragma unroll
                for (int r = 0; r < 4; r++)
                    Y4[wv][l15][q * 4 + r] = a4[r];
            }
        }
        __syncthreads();

        // ---- residuals: threads 0..15, one point each --------------------------
        if (tid < 16 && (base + tid) < npts) {
            const float* Yh = Y4[0][tid];
            const float* JX = Y4[1][tid];
            const float* JY = Y4[2][tid];
            const float* JT = Y4[3][tid];
            const float g1 = 1.5f;
            float rho = Yh[0] + b40, vx = Yh[1] + b41, vy = Yh[2] + b42;
            float Bx  = Yh[3] + b43, By = Yh[4] + b44, P  = Yh[5] + b45;
            float v2 = vx * vx + vy * vy;
            float dt_rho = JT[0];
            float dt_rhovx = dt_rho * vx + rho * JT[1];
            float dt_rhovy = dt_rho * vy + rho * JT[2];
            auto dE = [&](const float* J) {
                return J[5] * g1 + 0.5f * J[0] * v2 + rho * (vx * J[1] + vy * J[2]) + Bx * J[3] + By * J[4];
            };
            float dE_dx = dE(JX), dE_dy = dE(JY), dE_dt = dE(JT);
            float div_v = JX[1] + JY[2];
            float div_B = JX[3] + JY[4];
            float continuity = dt_rho + rho * div_v;
            float dPm_dx = JX[5] + Bx * JX[3] + By * JX[4];
            float dPm_dy = JY[5] + Bx * JY[3] + By * JY[4];
            float momentum_x = dt_rhovx + dPm_dx - (Bx * JX[3] + By * JY[3]);
            float momentum_y = dt_rhovy + dPm_dy - (Bx * JX[4] + By * JY[4]);
            auto dG = [&](const float* J) {
                return J[1] * By + vx * J[4] - J[2] * Bx - vy * J[3];
            };
            float induction_x = JT[3] + dG(JY);
            float induction_y = JT[4] - dG(JX);
            float E = P * g1 + 0.5f * rho * v2 + 0.5f * (Bx * Bx + By * By);
            float S = E + P + 0.5f * (Bx * Bx + By * By);
            float dS_dx = dE_dx + JX[5] + Bx * JX[3] + By * JX[4];
            float dS_dy = dE_dy + JY[5] + Bx * JY[3] + By * JY[4];
            float D = Bx * vx + By * vy;
            auto dD = [&](const float* J) {
                return J[3] * vx + Bx * J[1] + J[4] * vy + By * J[2];
            };
            float dFx_dx = dS_dx * vx + S * JX[1] - dD(JX) * Bx - D * JX[3];
            float dFy_dy = dS_dy * vy + S * JY[2] - dD(JY) * By - D * JY[4];
            float energy = dE_dt + dFx_dx + dFy_dy;
            vsum += wt0 * continuity * continuity
                  + wt1 * momentum_x * momentum_x
                  + wt2_ * momentum_y * momentum_y
                  + wt3_ * induction_x * induction_x
                  + wt4_ * induction_y * induction_y
                  + wt5 * energy * energy
                  + wt6 * div_B * div_B;
        }
        __syncthreads();   // Y4/cs safe to overwrite next tile
    }

    // ---- final reduction: vsum lives on tid 0..15 only -------------------------
    if (tid < 64) {
        #pragma unroll
        for (int off = 8; off >= 1; off >>= 1)
            vsum += __shfl_down(vsum, off, 64);
        if (tid == 0) atomicAdd(out, vsum * inv_n);
    }
}

extern "C" void kernel_launch(void* const* d_in, const int* in_sizes, int n_in,
                              void* d_out, int out_size, void* d_ws, size_t ws_size,
                              hipStream_t stream) {
    const float* coords = (const float*)d_in[0];
    const float* W1 = (const float*)d_in[1];
    const float* b1 = (const float*)d_in[2];
    const float* W2 = (const float*)d_in[3];
    const float* b2 = (const float*)d_in[4];
    const float* W3 = (const float*)d_in[5];
    const float* b3 = (const float*)d_in[6];
    const float* W4 = (const float*)d_in[7];
    const float* b4 = (const float*)d_in[8];
    const float* wts = (const float*)d_in[9];
    const int npts = in_sizes[0] / 3;

    ushort* Wt2 = (ushort*)d_ws;
    ushort* Wt3 = Wt2 + 65536;
    ushort* Wt4 = Wt3 + 65536;

    hipMemsetAsync(d_out, 0, sizeof(float), stream);
    prep_weights<<<256, 256, 0, stream>>>(W2, W3, W4, Wt2, Wt3, Wt4);
    mhd_fused<<<GRIDB, 256, 0, stream>>>(coords, W1, b1, b2, b3, b4, wts,
                                         Wt2, Wt3, Wt4, (float*)d_out, npts, 1.0f / npts);
}

// Round 3
// 247.836 us; speedup vs baseline: 1.5316x; 1.1977x over previous
//
#include <hip/hip_runtime.h>
#include <hip/hip_bf16.h>
#include <cstdint>

// MHD PINN loss, fully fused + persistent. N=131072 pts, H=256.
// Swapped-operand: D = W * X^T (m = neuron, n = 16 pts x 4 streams).
// Block = 512 thr (8 waves), grid = 256 (1 block/CU, 2 waves/SIMD).
// Each wave owns 32 output neurons; its W2/W3 slices live in registers.
// Streams: s=0 forward h, s=1..3 tangents d/dx,d/dy,d/dt; X row = s*16+p.

#define LDW 264   // X tile row stride in ushorts (132 words == 4 mod 32 -> 2-way max)
#define TPTS 16
#define GRIDB 256

typedef __attribute__((ext_vector_type(8))) short v8h;   // 8 x bf16
typedef __attribute__((ext_vector_type(4))) float v4f;

__device__ __forceinline__ ushort f2b(float f) {           // fp32 -> bf16 RNE
    uint32_t u = __float_as_uint(f);
    u = (u + 0x7fffu + ((u >> 16) & 1u)) >> 16;
    return (ushort)u;
}
__device__ __forceinline__ uint32_t pk2(float a, float b) { // packed cvt (v_cvt_pk_bf16_f32 on gfx950)
    union { __hip_bfloat162 h2; uint32_t u; } cv;
    cv.h2 = __float22bfloat162_rn(make_float2(a, b));
    return cv.u;
}
__device__ __forceinline__ float fast_tanh(float x) {
    float e = __expf(2.0f * x);
    return 1.0f - 2.0f * __builtin_amdgcn_rcpf(e + 1.0f);
}

// prep: W2,W3 (256x256 [k][n]) -> bf16 transposed Wt[n][k]; W4 (256x6) -> Wt4[16][256] padded
__global__ void prep_weights(const float* __restrict__ W2, const float* __restrict__ W3,
                             const float* __restrict__ W4,
                             ushort* __restrict__ Wt2, ushort* __restrict__ Wt3,
                             ushort* __restrict__ Wt4) {
    int idx = blockIdx.x * 256 + threadIdx.x;
    if (idx < 65536) {
        int k = idx >> 8, n = idx & 255;
        Wt2[n * 256 + k] = f2b(W2[k * 256 + n]);
        Wt3[n * 256 + k] = f2b(W3[k * 256 + n]);
    }
    if (idx < 4096) {
        int n = idx >> 8, k = idx & 255;
        Wt4[n * 256 + k] = (n < 6) ? f2b(W4[k * 6 + n]) : (ushort)0;
    }
}

// one hidden layer: D = W(32x256 slice) * src^T(256x64); src -> dst (ping-pong, no hazard)
__device__ __forceinline__ void dense_layer(const ushort* __restrict__ src,
                                            ushort* __restrict__ dst,
                                            const v8h (*wf)[8], const v4f* bs,
                                            int wv, int q, int l15) {
    v4f acc[2][4];
    #pragma unroll
    for (int a = 0; a < 2; a++)
        #pragma unroll
        for (int b = 0; b < 4; b++) {
            v4f z = {0.0f, 0.0f, 0.0f, 0.0f};
            acc[a][b] = z;
        }
    #pragma unroll
    for (int kk = 0; kk < 8; kk++) {
        v8h B[4];
        #pragma unroll
        for (int nt = 0; nt < 4; nt++)
            B[nt] = *(const v8h*)(&src[(nt * 16 + l15) * LDW + kk * 32 + q * 8]);
        #pragma unroll
        for (int mt = 0; mt < 2; mt++)
            #pragma unroll
            for (int nt = 0; nt < 4; nt++)
                acc[mt][nt] = __builtin_amdgcn_mfma_f32_16x16x32_bf16(wf[mt][kk], B[nt], acc[mt][nt], 0, 0, 0);
    }
    // D row (neuron) = mt*16 + q*4 + r, D col = nt*16 + l15 => stream s = nt, point p = l15.
    #pragma unroll
    for (int mt = 0; mt < 2; mt++) {
        const int colb = wv * 32 + mt * 16 + q * 4;
        v4f bb = bs[mt];
        float h0 = fast_tanh(acc[mt][0][0] + bb[0]);
        float h1 = fast_tanh(acc[mt][0][1] + bb[1]);
        float h2 = fast_tanh(acc[mt][0][2] + bb[2]);
        float h3 = fast_tanh(acc[mt][0][3] + bb[3]);
        float d0 = 1.0f - h0 * h0, d1 = 1.0f - h1 * h1;
        float d2 = 1.0f - h2 * h2, d3 = 1.0f - h3 * h3;
        uint2 w;
        w.x = pk2(h0, h1); w.y = pk2(h2, h3);
        *(uint2*)(&dst[l15 * LDW + colb]) = w;
        #pragma unroll
        for (int s = 1; s < 4; s++) {
            w.x = pk2(d0 * acc[mt][s][0], d1 * acc[mt][s][1]);
            w.y = pk2(d2 * acc[mt][s][2], d3 * acc[mt][s][3]);
            *(uint2*)(&dst[(s * 16 + l15) * LDW + colb]) = w;
        }
    }
}

__global__ __launch_bounds__(512, 2)
void mhd_fused(const float* __restrict__ coords,
               const float* __restrict__ W1, const float* __restrict__ b1,
               const float* __restrict__ b2, const float* __restrict__ b3,
               const float* __restrict__ b4,
               const float* __restrict__ wts,
               const ushort* __restrict__ Wt2, const ushort* __restrict__ Wt3,
               const ushort* __restrict__ Wt4,
               float* __restrict__ out, int npts, float inv_n) {
    __shared__ ushort Xs0[64 * LDW];
    __shared__ ushort Xs1[64 * LDW];
    __shared__ ushort W4s[16 * LDW];
    __shared__ float  cs[TPTS * 3];
    __shared__ float  Y4[4][TPTS][8];

    const int tid  = threadIdx.x;
    const int lane = tid & 63;
    const int wv   = tid >> 6;      // 0..7
    const int q    = lane >> 4;
    const int l15  = lane & 15;

    // ---- stage W4 (16x256, padded) into LDS ----------------------------------
    for (int idx = tid; idx < 16 * 256; idx += 512)
        W4s[(idx >> 8) * LDW + (idx & 255)] = Wt4[idx];

    // ---- weight fragments -> registers (wave owns 32 neurons) ----------------
    v8h w2f[2][8], w3f[2][8];
    v4f bs2[2], bs3[2];
    #pragma unroll
    for (int mt = 0; mt < 2; mt++) {
        const int nrow = (wv * 32 + mt * 16 + l15) * 256 + q * 8;
        #pragma unroll
        for (int kk = 0; kk < 8; kk++) {
            w2f[mt][kk] = *(const v8h*)(&Wt2[nrow + kk * 32]);
            w3f[mt][kk] = *(const v8h*)(&Wt3[nrow + kk * 32]);
        }
        bs2[mt] = *(const v4f*)(&b2[wv * 32 + mt * 16 + q * 4]);
        bs3[mt] = *(const v4f*)(&b3[wv * 32 + mt * 16 + q * 4]);
    }

    const int jj = tid & 255, ph = tid >> 8;
    const float l1w0 = W1[jj], l1w1 = W1[256 + jj], l1w2 = W1[512 + jj], l1b = b1[jj];
    const float b40 = b4[0], b41 = b4[1], b42 = b4[2], b43 = b4[3], b44 = b4[4], b45 = b4[5];
    const float wt0 = wts[0], wt1 = wts[1], wt2_ = wts[2], wt3_ = wts[3],
                wt4_ = wts[4], wt5 = wts[5], wt6 = wts[6];

    const int ntiles = (npts + TPTS - 1) / TPTS;
    float vsum = 0.0f;

    for (int tile = blockIdx.x; tile < ntiles; tile += GRIDB) {
        const int base = tile * TPTS;

        if (tid < TPTS * 3) {
            int p = tid / 3, c = tid % 3;
            int gp = base + p; if (gp >= npts) gp = npts - 1;
            cs[tid] = coords[gp * 3 + c];
        }
        __syncthreads();   // B1: cs ready; prev tile's Xs0 readers done

        // ---- layer 1 (3->256): col = jj, half ph does points ph*8..ph*8+7 ----
        #pragma unroll
        for (int pp = 0; pp < 8; pp++) {
            const int p = ph * 8 + pp;
            float x = cs[p * 3], y = cs[p * 3 + 1], t = cs[p * 3 + 2];
            float pre = fmaf(x, l1w0, fmaf(y, l1w1, fmaf(t, l1w2, l1b)));
            float h = fast_tanh(pre);
            float d = 1.0f - h * h;
            Xs0[p * LDW + jj]        = f2b(h);
            Xs0[(16 + p) * LDW + jj] = f2b(d * l1w0);
            Xs0[(32 + p) * LDW + jj] = f2b(d * l1w1);
            Xs0[(48 + p) * LDW + jj] = f2b(d * l1w2);
        }
        __syncthreads();   // B2

        dense_layer(Xs0, Xs1, w2f, bs2, wv, q, l15);   // L2: A -> B
        __syncthreads();   // B3
        dense_layer(Xs1, Xs0, w3f, bs3, wv, q, l15);   // L3: B -> A
        __syncthreads();   // B4

        // ---- layer 4: waves 0..3 handle stream wv ----------------------------
        if (wv < 4) {
            v4f a4 = {0.0f, 0.0f, 0.0f, 0.0f};
            #pragma unroll
            for (int kk = 0; kk < 8; kk++) {
                v8h A = *(const v8h*)(&W4s[l15 * LDW + kk * 32 + q * 8]);
                v8h B = *(const v8h*)(&Xs0[(wv * 16 + l15) * LDW + kk * 32 + q * 8]);
                a4 = __builtin_amdgcn_mfma_f32_16x16x32_bf16(A, B, a4, 0, 0, 0);
            }
            if (q < 2) {
                #pragma unroll
                for (int r = 0; r < 4; r++)
                    Y4[wv][l15][q * 4 + r] = a4[r];
            }
        }
        __syncthreads();   // B5: Y4 ready; Xs0 readers done

        // ---- residuals: wave-0 threads 0..15, one point each ------------------
        if (tid < 16 && (base + tid) < npts) {
            const float* Yh = Y4[0][tid];
            const float* JX = Y4[1][tid];
            const float* JY = Y4[2][tid];
            const float* JT = Y4[3][tid];
            const float g1 = 1.5f;
            float rho = Yh[0] + b40, vx = Yh[1] + b41, vy = Yh[2] + b42;
            float Bx  = Yh[3] + b43, By = Yh[4] + b44, P  = Yh[5] + b45;
            float v2 = vx * vx + vy * vy;
            float dt_rho = JT[0];
            float dt_rhovx = dt_rho * vx + rho * JT[1];
            float dt_rhovy = dt_rho * vy + rho * JT[2];
            auto dE = [&](const float* J) {
                return J[5] * g1 + 0.5f * J[0] * v2 + rho * (vx * J[1] + vy * J[2]) + Bx * J[3] + By * J[4];
            };
            float dE_dx = dE(JX), dE_dy = dE(JY), dE_dt = dE(JT);
            float div_v = JX[1] + JY[2];
            float div_B = JX[3] + JY[4];
            float continuity = dt_rho + rho * div_v;
            float dPm_dx = JX[5] + Bx * JX[3] + By * JX[4];
            float dPm_dy = JY[5] + Bx * JY[3] + By * JY[4];
            float momentum_x = dt_rhovx + dPm_dx - (Bx * JX[3] + By * JY[3]);
            float momentum_y = dt_rhovy + dPm_dy - (Bx * JX[4] + By * JY[4]);
            auto dG = [&](const float* J) {
                return J[1] * By + vx * J[4] - J[2] * Bx - vy * J[3];
            };
            float induction_x = JT[3] + dG(JY);
            float induction_y = JT[4] - dG(JX);
            float E = P * g1 + 0.5f * rho * v2 + 0.5f * (Bx * Bx + By * By);
            float S = E + P + 0.5f * (Bx * Bx + By * By);
            float dS_dx = dE_dx + JX[5] + Bx * JX[3] + By * JX[4];
            float dS_dy = dE_dy + JY[5] + Bx * JY[3] + By * JY[4];
            float D = Bx * vx + By * vy;
            auto dD = [&](const float* J) {
                return J[3] * vx + Bx * J[1] + J[4] * vy + By * J[2];
            };
            float dFx_dx = dS_dx * vx + S * JX[1] - dD(JX) * Bx - D * JX[3];
            float dFy_dy = dS_dy * vy + S * JY[2] - dD(JY) * By - D * JY[4];
            float energy = dE_dt + dFx_dx + dFy_dy;
            vsum += wt0 * continuity * continuity
                  + wt1 * momentum_x * momentum_x
                  + wt2_ * momentum_y * momentum_y
                  + wt3_ * induction_x * induction_x
                  + wt4_ * induction_y * induction_y
                  + wt5 * energy * energy
                  + wt6 * div_B * div_B;
        }
        // no extra barrier: next-iter B1 orders Y4/cs/Xs0 reuse
    }

    if (tid < 64) {
        #pragma unroll
        for (int off = 8; off >= 1; off >>= 1)
            vsum += __shfl_down(vsum, off, 64);
        if (tid == 0) atomicAdd(out, vsum * inv_n);
    }
}

extern "C" void kernel_launch(void* const* d_in, const int* in_sizes, int n_in,
                              void* d_out, int out_size, void* d_ws, size_t ws_size,
                              hipStream_t stream) {
    const float* coords = (const float*)d_in[0];
    const float* W1 = (const float*)d_in[1];
    const float* b1 = (const float*)d_in[2];
    const float* W2 = (const float*)d_in[3];
    const float* b2 = (const float*)d_in[4];
    const float* W3 = (const float*)d_in[5];
    const float* b3 = (const float*)d_in[6];
    const float* W4 = (const float*)d_in[7];
    const float* b4 = (const float*)d_in[8];
    const float* wts = (const float*)d_in[9];
    const int npts = in_sizes[0] / 3;

    ushort* Wt2 = (ushort*)d_ws;
    ushort* Wt3 = Wt2 + 65536;
    ushort* Wt4 = Wt3 + 65536;

    hipMemsetAsync(d_out, 0, sizeof(float), stream);
    prep_weights<<<256, 256, 0, stream>>>(W2, W3, W4, Wt2, Wt3, Wt4);
    mhd_fused<<<GRIDB, 512, 0, stream>>>(coords, W1, b1, b2, b3, b4, wts,
                                         Wt2, Wt3, Wt4, (float*)d_out, npts, 1.0f / npts);
}